// Round 5
// baseline (679.023 us; speedup 1.0000x reference)
//
#include <hip/hip_runtime.h>
#include <hip/hip_bf16.h>

#define GH 52
#define GW 92
#define BP 19136
#define HP 364
#define WP 644
#define HIN 360
#define WIN_ 640

// guarded tensors
#define Y32H 368   // HP + 4 (pad 2 top/bottom)
#define Y32W 648   // WP + 4
#define Y64H 365   // HP + 1 (pad 1 top)
#define Y64W 645   // WP + 1 (pad 1 left)

typedef __attribute__((ext_vector_type(8))) short short8;
typedef __attribute__((ext_vector_type(4))) float f32x4;

__device__ __constant__ float c_mean[3] = {114.444f, 111.4605f, 103.02f};

// workspace layout (bytes)
// region [0,120537600) = y64p; earlier epochs: feat1/feat2/kb2 (dead before conv3 writes y64p)
#define OFF_Y64P  0ULL            // bf16 4 x 365 x 645 x 64 (120.5 MB)
#define OFF_FEAT1 0ULL            // bf16 [25pos][BP][64c] (61.2 MB), dead after conv2
#define OFF_FEAT2 61235200ULL     // bf16 [9po][BP][64oc]  (22.0 MB), dead after gemm
#define OFF_KB2   83279872ULL     // bf16 BP x 896 (34.3 MB), dead after apply
#define OFF_Y32P  120537600ULL    // bf16 4 x 368 x 648 x 32 (61.0 MB)
#define OFF_BMG   181592576ULL    // fp32 merged+reordered bias [896]
#define OFF_W1T   181596160ULL    // fp32 27x64
#define OFF_W2B   181603072ULL    // bf16 [9tap][64oc][64c]
#define OFF_WKB   181676800ULL    // bf16 [896n'][576k]  n' = k27*32+fch (k-major)
#define OFF_W3B   182708992ULL    // bf16 [25tap][64oc][32c]
#define OFF_W4B   182811392ULL    // bf16 [9tap][2kh][16n][32c]
#define WS_NEED   182833920ULL

static __device__ __forceinline__ short bf16bits(float v) {
    __hip_bfloat16 h = __float2bfloat16(v);
    return *reinterpret_cast<short*>(&h);
}
static __device__ __forceinline__ float bits2f(short s) {
    __hip_bfloat16 h = *reinterpret_cast<__hip_bfloat16*>(&s);
    return __bfloat162float(h);
}

// ---------------- prep: weight repacks + reordered merged bias ----------------------------
__global__ __launch_bounds__(256) void k_prep(
    const float* __restrict__ w1, float* __restrict__ w1t,
    const float* __restrict__ w2, short* __restrict__ w2b,
    const float* __restrict__ wk, const float* __restrict__ wb, short* __restrict__ wkb,
    const float* __restrict__ bk, const float* __restrict__ bb, float* __restrict__ bmg,
    const float* __restrict__ w3, short* __restrict__ w3b,
    const float* __restrict__ w4, short* __restrict__ w4b)
{
    int i = blockIdx.x * 256 + threadIdx.x;
    if (i < 1728) { int oc = i / 27, k = i % 27; w1t[k*64 + oc] = w1[i]; }
    if (i < 896) {
        // bias in n' order: n'<864 -> channel c864 = fch*27 + k27, fch=n'&31, k27=n'>>5
        bmg[i] = (i < 864) ? bk[(i & 31)*27 + (i >> 5)] : bb[i - 864];
    }
    if (i < 36864) {
        int c = i & 63; int rest = i >> 6; int oc = rest & 63; int tap = rest >> 6;
        int ky = tap / 3, kx = tap % 3;
        w2b[i] = bf16bits(w2[((oc*64 + c)*3 + ky)*3 + kx]);
    }
    if (i < 516096) {
        // i = n'*576 + po*64 + f ; source k-index = f*9 + po
        int n = i / 576, r = i % 576;
        int po = r >> 6, f = r & 63;
        int ks = f*9 + po;
        float v;
        if (n < 864) { int fch = n & 31, k27 = n >> 5; v = wk[(fch*27 + k27)*576 + ks]; }
        else v = wb[(n - 864)*576 + ks];
        wkb[i] = bf16bits(v);
    }
    if (i < 51200) {
        int c = i & 31; int rest = i >> 5; int oc = rest & 63; int tap = rest >> 6;
        int ky = tap / 5, kx = tap % 5;
        w3b[i] = bf16bits(w3[((oc*32 + c)*5 + ky)*5 + kx]);
    }
    if (i < 9216) {
        int c = i & 31; int rest = i >> 5; int n = rest & 15; rest >>= 4;
        int kh = rest & 1; int tap = rest >> 1;
        int ky = tap / 3, kx = tap % 3;
        float v = 0.f;
        if (n < 12) v = w4[((n*64 + kh*32 + c)*3 + ky)*3 + kx];
        w4b[i] = bf16bits(v);
    }
}

// ---------------- zero y32p guard ring (exclusive region; runs early) ---------------------
__global__ __launch_bounds__(256) void k_zg32(short* __restrict__ y32p)
{
    int u = blockIdx.x * 256 + threadIdx.x;     // 64768 uint4 writes
    if (u >= 64768) return;
    int b = u / 16192, r = u % 16192;
    int pxi = r >> 2, sub = r & 3;
    int row, col;
    if (pxi < 1296)      { row = pxi / 648;        col = pxi % 648; }            // rows 0,1
    else if (pxi < 2592) { row = 366 + (pxi-1296)/648; col = (pxi-1296) % 648; } // rows 366,367
    else {
        int s = pxi - 2592;                    // 1456 = 364 rows x 4 cols
        row = 2 + (s >> 2);
        int c4 = s & 3;
        col = (c4 < 2) ? c4 : (644 + c4);      // cols 0,1,646,647
    }
    uint4 z = make_uint4(0u,0u,0u,0u);
    *reinterpret_cast<uint4*>(y32p + (((size_t)b*Y32H + row)*Y32W + col)*32 + sub*8) = z;
}

// ---------------- zero y64p guard (row0 + col0); MUST run after k_apply (aliasing) --------
__global__ __launch_bounds__(256) void k_zg64(short* __restrict__ y64p)
{
    int u = blockIdx.x * 256 + threadIdx.x;     // 32288 uint4 writes
    if (u >= 32288) return;
    int b = u / 8072, r = u % 8072;
    int pxi = r >> 3, sub = r & 7;
    int row, col;
    if (pxi < 645) { row = 0; col = pxi; }
    else           { row = pxi - 645 + 1; col = 0; }
    uint4 z = make_uint4(0u,0u,0u,0u);
    *reinterpret_cast<uint4*>(y64p + (((size_t)b*Y64H + row)*Y64W + col)*64 + sub*8) = z;
}

// ---------------- conv1: patch extract + 3->64 3x3 VALID (7->5) -> feat1 [pos][patch][64c] -
__global__ __launch_bounds__(256) void k_conv1(
    const float* __restrict__ x, const float* __restrict__ w1t, const float* __restrict__ b1,
    short* __restrict__ feat1)
{
    __shared__ float sp[16][148];
    const int tid = threadIdx.x;
    const int p0 = blockIdx.x * 16;

    for (int t = tid; t < 16*147; t += 256) {
        int p = t / 147, r = t % 147;
        int c = r / 49, rr = r % 49;
        int i = rr / 7, j = rr % 7;
        int pg = p0 + p;
        int b = pg / (GH*GW), rem = pg % (GH*GW);
        int gy = rem / GW, gx = rem % GW;
        int yy = gy*7 + i, xx = gx*7 + j;
        float v = 0.f;
        if (yy < HIN && xx < WIN_) v = x[((b*3 + c)*HIN + yy)*WIN_ + xx] - c_mean[c];
        sp[p][r] = v;
    }
    __syncthreads();

    for (int t = tid; t < 3200; t += 256) {
        int ocg = t & 7, p = (t >> 3) & 15, pos = t >> 7;
        int pi = pos / 5, pj = pos % 5;
        float acc[8];
        #pragma unroll
        for (int u = 0; u < 8; ++u) acc[u] = b1[ocg*8 + u];
        #pragma unroll
        for (int c = 0; c < 3; ++c)
            #pragma unroll
            for (int ki = 0; ki < 3; ++ki)
                #pragma unroll
                for (int kj = 0; kj < 3; ++kj) {
                    float fv = sp[p][c*49 + (pi+ki)*7 + (pj+kj)];
                    const float* wr = w1t + (c*9 + ki*3 + kj)*64 + ocg*8;
                    const float4 wa = *reinterpret_cast<const float4*>(wr);
                    const float4 wb4 = *reinterpret_cast<const float4*>(wr + 4);
                    acc[0] += fv*wa.x;  acc[1] += fv*wa.y;  acc[2] += fv*wa.z;  acc[3] += fv*wa.w;
                    acc[4] += fv*wb4.x; acc[5] += fv*wb4.y; acc[6] += fv*wb4.z; acc[7] += fv*wb4.w;
                }
        short8 pack;
        #pragma unroll
        for (int u = 0; u < 8; ++u) pack[u] = bf16bits(fmaxf(acc[u], 0.f));
        *reinterpret_cast<short8*>(feat1 + (size_t)pos*(BP*64) + (size_t)(p0 + p)*64 + ocg*8) = pack;
    }
}

// ---------------- conv2: per-tap MFMA, LDS-free -------------------------------------------
__global__ __launch_bounds__(256) void k_conv2(
    const short* __restrict__ feat1, const short* __restrict__ w2b,
    const float* __restrict__ b2, short* __restrict__ feat2)
{
    const int tid = threadIdx.x;
    const int wv = tid >> 6, lane = tid & 63;
    const int n16 = lane & 15, q = lane >> 4;
    const int po = blockIdx.y;
    const int pi = po / 3, pj = po % 3;
    const int p0 = blockIdx.x * 128 + wv * 32;

    f32x4 acc[4][2];
    #pragma unroll
    for (int j = 0; j < 4; ++j) {
        float4 bj = *reinterpret_cast<const float4*>(b2 + j*16 + q*4);
        f32x4 bi = {bj.x, bj.y, bj.z, bj.w};
        acc[j][0] = bi; acc[j][1] = bi;
    }

    for (int ki = 0; ki < 3; ++ki)
        for (int kj = 0; kj < 3; ++kj) {
            const int tap = ki*3 + kj;
            const size_t base = (size_t)((pi+ki)*5 + (pj+kj)) * (BP*64);
            #pragma unroll
            for (int ks = 0; ks < 2; ++ks) {
                short8 af[4];
                #pragma unroll
                for (int j = 0; j < 4; ++j)
                    af[j] = *reinterpret_cast<const short8*>(w2b + (tap*64 + j*16 + n16)*64 + ks*32 + q*8);
                short8 bf[2];
                #pragma unroll
                for (int nt = 0; nt < 2; ++nt) {
                    int pr = p0 + nt*16 + n16; pr = (pr < BP) ? pr : (BP-1);
                    bf[nt] = *reinterpret_cast<const short8*>(feat1 + base + (size_t)pr*64 + ks*32 + q*8);
                }
                #pragma unroll
                for (int j = 0; j < 4; ++j)
                    #pragma unroll
                    for (int nt = 0; nt < 2; ++nt)
                        acc[j][nt] = __builtin_amdgcn_mfma_f32_16x16x32_bf16(af[j], bf[nt], acc[j][nt], 0, 0, 0);
            }
        }

    #pragma unroll
    for (int nt = 0; nt < 2; ++nt) {
        int pr = p0 + nt*16 + n16;
        if (pr >= BP) continue;
        #pragma unroll
        for (int j = 0; j < 4; ++j) {
            short4 pk;
            pk.x = bf16bits(fmaxf(acc[j][nt][0], 0.f));
            pk.y = bf16bits(fmaxf(acc[j][nt][1], 0.f));
            pk.z = bf16bits(fmaxf(acc[j][nt][2], 0.f));
            pk.w = bf16bits(fmaxf(acc[j][nt][3], 0.f));
            *reinterpret_cast<short4*>(feat2 + (size_t)po*(BP*64) + (size_t)pr*64 + j*16 + q*4) = pk;
        }
    }
}

// ---------------- GEMM MFMA: kb2(bf16) = feat2 @ wkb^T + bias -----------------------------
__global__ __launch_bounds__(256) void k_gemm(
    const short* __restrict__ feat2, const short* __restrict__ wkb,
    const float* __restrict__ bmg, short* __restrict__ kb2)
{
    __shared__ __align__(16) short As[128*40];
    __shared__ __align__(16) short Bs[128*40];
    const int tid = threadIdx.x;
    const int p0 = blockIdx.x * 128, n0 = blockIdx.y * 128;
    const int wv = tid >> 6, lane = tid & 63;
    const int n16 = lane & 15, q = lane >> 4;
    const int wm = wv & 1, wn = wv >> 1;

    f32x4 acc[4][4] = {};

    for (int k0 = 0; k0 < 576; k0 += 32) {
        const int po = k0 >> 6, cb = k0 & 63;
        for (int t = tid; t < 512; t += 256) {
            int row = t >> 2, seg = t & 3;
            uint4 a = *reinterpret_cast<const uint4*>(wkb + (size_t)(n0 + row)*576 + k0 + seg*8);
            int pr = p0 + row; pr = (pr < BP) ? pr : (BP-1);
            uint4 b = *reinterpret_cast<const uint4*>(feat2 + (size_t)po*(BP*64) + (size_t)pr*64 + cb + seg*8);
            *reinterpret_cast<uint4*>(&As[row*40 + seg*8]) = a;
            *reinterpret_cast<uint4*>(&Bs[row*40 + seg*8]) = b;
        }
        __syncthreads();
        short8 af[4], bf[4];
        #pragma unroll
        for (int mt = 0; mt < 4; ++mt)
            af[mt] = *reinterpret_cast<const short8*>(&As[(wm*64 + mt*16 + n16)*40 + q*8]);
        #pragma unroll
        for (int nt = 0; nt < 4; ++nt)
            bf[nt] = *reinterpret_cast<const short8*>(&Bs[(wn*64 + nt*16 + n16)*40 + q*8]);
        #pragma unroll
        for (int mt = 0; mt < 4; ++mt)
            #pragma unroll
            for (int nt = 0; nt < 4; ++nt)
                acc[mt][nt] = __builtin_amdgcn_mfma_f32_16x16x32_bf16(af[mt], bf[nt], acc[mt][nt], 0, 0, 0);
        __syncthreads();
    }

    #pragma unroll
    for (int nt = 0; nt < 4; ++nt) {
        int pr = p0 + wn*64 + nt*16 + n16;
        if (pr >= BP) continue;
        #pragma unroll
        for (int mt = 0; mt < 4; ++mt) {
            int nb = n0 + wm*64 + mt*16 + q*4;
            float4 bs = *reinterpret_cast<const float4*>(bmg + nb);
            short4 pk;
            pk.x = bf16bits(acc[mt][nt][0] + bs.x);
            pk.y = bf16bits(acc[mt][nt][1] + bs.y);
            pk.z = bf16bits(acc[mt][nt][2] + bs.z);
            pk.w = bf16bits(acc[mt][nt][3] + bs.w);
            *reinterpret_cast<short4*>(kb2 + (size_t)pr*896 + nb) = pk;
        }
    }
}

// ---------------- apply predicted 3x3x3->32 kernel per patch -> y32p interior -------------
__global__ __launch_bounds__(256) void k_apply(
    const float* __restrict__ x, const short* __restrict__ kb2, short* __restrict__ y32p)
{
    __shared__ float pp[3][9][9];
    __shared__ __align__(16) short klb[896];    // [k27][32f] + bias at 864
    const int p = blockIdx.x;
    const int tid = threadIdx.x;
    const int b = p / (GH*GW), rem = p % (GH*GW);
    const int gy = rem / GW, gx = rem % GW;

    for (int t = tid; t < 243; t += 256) ((float*)pp)[t] = 0.f;
    if (tid < 112)
        *reinterpret_cast<uint4*>(&klb[tid*8]) =
            *reinterpret_cast<const uint4*>(kb2 + (size_t)p*896 + tid*8);
    __syncthreads();
    for (int t = tid; t < 147; t += 256) {
        int c = t / 49, r = t % 49, i = r / 7, j = r % 7;
        int yy = gy*7 + i, xx = gx*7 + j;
        float v = 0.f;
        if (yy < HIN && xx < WIN_) v = x[((b*3 + c)*HIN + yy)*WIN_ + xx] - c_mean[c];
        pp[c][i+1][j+1] = v;
    }
    __syncthreads();

    if (tid < 196) {
        int pos = tid % 49, fg = tid / 49;
        int h = pos / 7, w = pos % 7;
        float win[27];
        #pragma unroll
        for (int c = 0; c < 3; ++c)
            #pragma unroll
            for (int i = 0; i < 3; ++i)
                #pragma unroll
                for (int j = 0; j < 3; ++j)
                    win[c*9 + i*3 + j] = pp[c][h+i][w+j];
        float acc[8];
        #pragma unroll
        for (int u = 0; u < 8; ++u) acc[u] = bits2f(klb[864 + fg*8 + u]);
        #pragma unroll
        for (int k = 0; k < 27; ++k) {
            float v = win[k];
            short8 wr = *reinterpret_cast<const short8*>(&klb[k*32 + fg*8]);
            #pragma unroll
            for (int u = 0; u < 8; ++u) acc[u] += v * bits2f(wr[u]);
        }
        int yy = gy*7 + h, xx = gx*7 + w;
        short8 pack;
        #pragma unroll
        for (int u = 0; u < 8; ++u) pack[u] = bf16bits(acc[u]);
        *reinterpret_cast<short8*>(
            y32p + (((size_t)b*Y32H + yy + 2)*Y32W + xx + 2)*32 + fg*8) = pack;
    }
}

// ---------------- conv3: LDS-free streaming MFMA, 32->64 5x5 + relu -----------------------
// wave = 4 rows x 16 px x 64 oc; B-frags = coalesced 1KB global loads (L1 kx-sliding reuse)
__global__ __launch_bounds__(256) void k_conv3(
    const short* __restrict__ y32p, const short* __restrict__ w3b,
    const float* __restrict__ b3, short* __restrict__ y64p)
{
    const int tid = threadIdx.x;
    const int wv = tid >> 6, lane = tid & 63;
    const int n16 = lane & 15, q = lane >> 4;
    const int x0 = blockIdx.x * 16, y0 = blockIdx.y * 16 + wv * 4, b = blockIdx.z;
    const short* src = y32p + (size_t)b * Y32H * Y32W * 32;
    const int cx = x0 + n16;

    f32x4 acc[4][4];
    #pragma unroll
    for (int j = 0; j < 4; ++j) {
        float4 bj = *reinterpret_cast<const float4*>(b3 + j*16 + q*4);
        f32x4 bi = {bj.x, bj.y, bj.z, bj.w};
        #pragma unroll
        for (int i = 0; i < 4; ++i) acc[i][j] = bi;
    }

    for (int ky = 0; ky < 5; ++ky) {
        #pragma unroll
        for (int kx = 0; kx < 5; ++kx) {
            const int tap = ky*5 + kx;
            short8 afw[4];
            #pragma unroll
            for (int j = 0; j < 4; ++j)
                afw[j] = *reinterpret_cast<const short8*>(w3b + (tap*64 + j*16 + n16)*32 + q*8);
            short8 bfa[4];
            #pragma unroll
            for (int i = 0; i < 4; ++i) {
                int ry = y0 + i + ky; ry = (ry < Y32H) ? ry : (Y32H - 1);
                bfa[i] = *reinterpret_cast<const short8*>(src + ((size_t)ry*Y32W + cx + kx)*32 + q*8);
            }
            #pragma unroll
            for (int i = 0; i < 4; ++i)
                #pragma unroll
                for (int j = 0; j < 4; ++j)
                    acc[i][j] = __builtin_amdgcn_mfma_f32_16x16x32_bf16(afw[j], bfa[i], acc[i][j], 0, 0, 0);
        }
    }

    const int ox = x0 + n16;
    if (ox < WP) {
        #pragma unroll
        for (int i = 0; i < 4; ++i) {
            int oy = y0 + i;
            if (oy >= HP) continue;
            short* dst = y64p + (((size_t)b*Y64H + oy + 1)*Y64W + ox + 1)*64;
            #pragma unroll
            for (int j = 0; j < 4; ++j) {
                short4 pk;
                pk.x = bf16bits(fmaxf(acc[i][j][0], 0.f));
                pk.y = bf16bits(fmaxf(acc[i][j][1], 0.f));
                pk.z = bf16bits(fmaxf(acc[i][j][2], 0.f));
                pk.w = bf16bits(fmaxf(acc[i][j][3], 0.f));
                *reinterpret_cast<short4*>(dst + j*16 + q*4) = pk;
            }
        }
    }
}

// ---------------- conv4: LDS-free streaming MFMA, 64->12 3x3 + pixel-shuffle + mean -------
__global__ __launch_bounds__(256) void k_conv4(
    const short* __restrict__ y64p, const short* __restrict__ w4b,
    const float* __restrict__ b4, float* __restrict__ out)
{
    const int tid = threadIdx.x;
    const int wv = tid >> 6, lane = tid & 63;
    const int n16 = lane & 15, q = lane >> 4;
    const int x0 = blockIdx.x * 16, y0 = blockIdx.y * 16 + wv * 4, b = blockIdx.z;
    const short* src = y64p + (size_t)b * Y64H * Y64W * 64;
    const int cx = x0 + n16;

    f32x4 acc[4];
    {
        f32x4 bi = {0.f, 0.f, 0.f, 0.f};
        if (q < 3) {
            float4 bq = *reinterpret_cast<const float4*>(b4 + q*4);
            bi = {bq.x, bq.y, bq.z, bq.w};
        }
        #pragma unroll
        for (int i = 0; i < 4; ++i) acc[i] = bi;
    }

    for (int ky = 0; ky < 3; ++ky) {
        #pragma unroll
        for (int kx = 0; kx < 3; ++kx) {
            const int tap = ky*3 + kx;
            short8 af0 = *reinterpret_cast<const short8*>(w4b + ((tap*2 + 0)*16 + n16)*32 + q*8);
            short8 af1 = *reinterpret_cast<const short8*>(w4b + ((tap*2 + 1)*16 + n16)*32 + q*8);
            #pragma unroll
            for (int i = 0; i < 4; ++i) {
                int ry = y0 + i + ky; ry = (ry < Y64H) ? ry : (Y64H - 1);
                const short* pr = src + ((size_t)ry*Y64W + cx + kx)*64;
                short8 a0 = *reinterpret_cast<const short8*>(pr + q*8);
                short8 a1 = *reinterpret_cast<const short8*>(pr + 32 + q*8);
                acc[i] = __builtin_amdgcn_mfma_f32_16x16x32_bf16(af0, a0, acc[i], 0, 0, 0);
                acc[i] = __builtin_amdgcn_mfma_f32_16x16x32_bf16(af1, a1, acc[i], 0, 0, 0);
            }
        }
    }

    if (q < 3) {
        const int xx = x0 + n16;
        const float m = c_mean[q];
        #pragma unroll
        for (int i = 0; i < 4; ++i) {
            int yy = y0 + i;
            if (yy >= HIN) continue;
            size_t r0 = ((size_t)(b*3 + q)*720 + yy*2)*1280 + xx*2;
            float2 s0 = {acc[i][0] + m, acc[i][1] + m};
            float2 s1 = {acc[i][2] + m, acc[i][3] + m};
            *reinterpret_cast<float2*>(out + r0) = s0;
            *reinterpret_cast<float2*>(out + r0 + 1280) = s1;
        }
    }
}

extern "C" void kernel_launch(void* const* d_in, const int* in_sizes, int n_in,
                              void* d_out, int out_size, void* d_ws, size_t ws_size,
                              hipStream_t stream) {
    const float* x  = (const float*)d_in[0];
    const float* w1 = (const float*)d_in[1];
    const float* b1 = (const float*)d_in[2];
    const float* w2 = (const float*)d_in[3];
    const float* b2 = (const float*)d_in[4];
    const float* wk = (const float*)d_in[5];
    const float* bk = (const float*)d_in[6];
    const float* wb = (const float*)d_in[7];
    const float* bb = (const float*)d_in[8];
    const float* w3 = (const float*)d_in[9];
    const float* b3 = (const float*)d_in[10];
    const float* w4 = (const float*)d_in[11];
    const float* b4 = (const float*)d_in[12];
    float* out = (float*)d_out;

    if (ws_size < WS_NEED) return;

    char* ws = (char*)d_ws;
    short* feat1 = (short*)(ws + OFF_FEAT1);
    short* feat2 = (short*)(ws + OFF_FEAT2);
    short* kb2   = (short*)(ws + OFF_KB2);
    short* y32p  = (short*)(ws + OFF_Y32P);
    short* y64p  = (short*)(ws + OFF_Y64P);
    float* bmg = (float*)(ws + OFF_BMG);
    float* w1t = (float*)(ws + OFF_W1T);
    short* w2b = (short*)(ws + OFF_W2B);
    short* wkb = (short*)(ws + OFF_WKB);
    short* w3b = (short*)(ws + OFF_W3B);
    short* w4b = (short*)(ws + OFF_W4B);

    k_prep <<<2016, 256, 0, stream>>>(w1, w1t, w2, w2b, wk, wb, wkb, bk, bb, bmg, w3, w3b, w4, w4b);
    k_zg32 <<<254, 256, 0, stream>>>(y32p);
    k_conv1<<<BP/16, 256, 0, stream>>>(x, w1t, b1, feat1);
    k_conv2<<<dim3(150, 9), 256, 0, stream>>>(feat1, w2b, b2, feat2);
    k_gemm <<<dim3(150, 7), 256, 0, stream>>>(feat2, wkb, bmg, kb2);
    k_apply<<<BP, 256, 0, stream>>>(x, kb2, y32p);
    k_zg64 <<<127, 256, 0, stream>>>(y64p);   // after apply: y64p aliases feat1/feat2/kb2
    k_conv3<<<dim3(41, 23, 4), 256, 0, stream>>>(y32p, w3b, b3, y64p);
    k_conv4<<<dim3(40, 23, 4), 256, 0, stream>>>(y64p, w4b, b4, out);
}

// Round 7
// 456.051 us; speedup vs baseline: 1.4889x; 1.4889x over previous
//
#include <hip/hip_runtime.h>
#include <hip/hip_bf16.h>

#define GH 52
#define GW 92
#define BP 19136
#define HP 364
#define WP 644
#define HIN 360
#define WIN_ 640

// guarded tensors
#define Y32H 368   // HP + 4 (pad 2 top/bottom)
#define Y32W 648   // WP + 4
#define Y64H 365   // HP + 1 (pad 1 top)
#define Y64W 645   // WP + 1 (pad 1 left)

typedef __attribute__((ext_vector_type(8))) short short8;
typedef __attribute__((ext_vector_type(4))) float f32x4;

__device__ __constant__ float c_mean[3] = {114.444f, 111.4605f, 103.02f};

// workspace layout (bytes)
#define OFF_FEAT1 0ULL            // bf16 [25pos][BP][64c] (61.2 MB), dead after conv2
#define OFF_FEAT2 61235200ULL     // bf16 [9po][BP][64f]  (22.0 MB), dead after gemm
#define OFF_KB2   83279872ULL     // bf16 BP x 1024 rows [32f][32k] (39.2 MB), dead after apply
#define OFF_Y64P  0ULL            // bf16 4 x 365 x 645 x 64 (120.5 MB) -- aliases feat1/feat2/kb2
#define OFF_Y32P  122470400ULL    // bf16 4 x 368 x 648 x 32 (61.0 MB)
#define OFF_BMG   183517184ULL    // fp32 merged bias [1024]
#define OFF_W1T   183521280ULL    // fp32 27x64
#define OFF_W2B   183528192ULL    // bf16 [9tap][64oc][64c]
#define OFF_WKB   183601920ULL    // bf16 [1024n'][576k]  n' = f*32+k (k=27 -> wb row, k>27 zero)
#define OFF_W3B   184781568ULL    // bf16 [25tap][64oc][32c]
#define OFF_W4B   184883968ULL    // bf16 [9tap][2kh][16n][32c]
#define WS_NEED   184902400ULL

static __device__ __forceinline__ short bf16bits(float v) {
    __hip_bfloat16 h = __float2bfloat16(v);
    return *reinterpret_cast<short*>(&h);
}
static __device__ __forceinline__ float bits2f(short s) {
    __hip_bfloat16 h = *reinterpret_cast<__hip_bfloat16*>(&s);
    return __bfloat162float(h);
}

// ---------------- prep: weight repacks + merged bias --------------------------------------
__global__ __launch_bounds__(256) void k_prep(
    const float* __restrict__ w1, float* __restrict__ w1t,
    const float* __restrict__ w2, short* __restrict__ w2b,
    const float* __restrict__ wk, const float* __restrict__ wb, short* __restrict__ wkb,
    const float* __restrict__ bk, const float* __restrict__ bb, float* __restrict__ bmg,
    const float* __restrict__ w3, short* __restrict__ w3b,
    const float* __restrict__ w4, short* __restrict__ w4b)
{
    int i = blockIdx.x * 256 + threadIdx.x;
    if (i < 1728) { int oc = i / 27, k = i % 27; w1t[k*64 + oc] = w1[i]; }
    if (i < 1024) {
        int f = i >> 5, k = i & 31;
        bmg[i] = (k < 27) ? bk[f*27 + k] : ((k == 27) ? bb[f] : 0.f);
    }
    if (i < 36864) {
        int c = i & 63; int rest = i >> 6; int oc = rest & 63; int tap = rest >> 6;
        int ky = tap / 3, kx = tap % 3;
        w2b[i] = bf16bits(w2[((oc*64 + c)*3 + ky)*3 + kx]);
    }
    if (i < 589824) {
        // i = n'*576 + po*64 + fch ; source k-index ks = fch*9 + po
        int n = i / 576, r = i % 576;
        int po = r >> 6, fch = r & 63;
        int ks = fch*9 + po;
        int f = n >> 5, k = n & 31;
        float v = 0.f;
        if (k < 27)       v = wk[(f*27 + k)*576 + ks];
        else if (k == 27) v = wb[f*576 + ks];
        wkb[i] = bf16bits(v);
    }
    if (i < 51200) {
        int c = i & 31; int rest = i >> 5; int oc = rest & 63; int tap = rest >> 6;
        int ky = tap / 5, kx = tap % 5;
        w3b[i] = bf16bits(w3[((oc*32 + c)*5 + ky)*5 + kx]);
    }
    if (i < 9216) {
        int c = i & 31; int rest = i >> 5; int n = rest & 15; rest >>= 4;
        int kh = rest & 1; int tap = rest >> 1;
        int ky = tap / 3, kx = tap % 3;
        float v = 0.f;
        if (n < 12) v = w4[((n*64 + kh*32 + c)*3 + ky)*3 + kx];
        w4b[i] = bf16bits(v);
    }
}

// ---------------- zero y32p guard ring (exclusive region; safe anytime before apply/conv3) -
__global__ __launch_bounds__(256) void k_zg32(short* __restrict__ y32p)
{
    int u = blockIdx.x * 256 + threadIdx.x;     // 64768 uint4 writes
    if (u >= 64768) return;
    int b = u / 16192, r = u % 16192;
    int pxi = r >> 2, sub = r & 3;
    int row, col;
    if (pxi < 1296)      { row = pxi / 648;        col = pxi % 648; }
    else if (pxi < 2592) { row = 366 + (pxi-1296)/648; col = (pxi-1296) % 648; }
    else {
        int s = pxi - 2592;
        row = 2 + (s >> 2);
        int c4 = s & 3;
        col = (c4 < 2) ? c4 : (644 + c4);
    }
    uint4 z = make_uint4(0u,0u,0u,0u);
    *reinterpret_cast<uint4*>(y32p + (((size_t)b*Y32H + row)*Y32W + col)*32 + sub*8) = z;
}

// ---------------- zero y64p guard (row0 + col0) -------------------------------------------
// y64p [0,120.5MB) aliases feat1/feat2/kb2 -> MUST run only after k_apply (all three dead).
__global__ __launch_bounds__(256) void k_zg64(short* __restrict__ y64p)
{
    int u = blockIdx.x * 256 + threadIdx.x;     // 32288 uint4 writes
    if (u >= 32288) return;
    int b = u / 8072, r = u % 8072;
    int pxi = r >> 3, sub = r & 7;
    int row, col;
    if (pxi < 645) { row = 0; col = pxi; }
    else           { row = pxi - 645 + 1; col = 0; }
    uint4 z = make_uint4(0u,0u,0u,0u);
    *reinterpret_cast<uint4*>(y64p + (((size_t)b*Y64H + row)*Y64W + col)*64 + sub*8) = z;
}

// ---------------- conv1: patch extract + 3->64 3x3 VALID (7->5) -> feat1 [pos][patch][64c] -
__global__ __launch_bounds__(256) void k_conv1(
    const float* __restrict__ x, const float* __restrict__ w1t, const float* __restrict__ b1,
    short* __restrict__ feat1)
{
    __shared__ float sp[16][148];
    const int tid = threadIdx.x;
    const int p0 = blockIdx.x * 16;

    for (int t = tid; t < 16*147; t += 256) {
        int p = t / 147, r = t % 147;
        int c = r / 49, rr = r % 49;
        int i = rr / 7, j = rr % 7;
        int pg = p0 + p;
        int b = pg / (GH*GW), rem = pg % (GH*GW);
        int gy = rem / GW, gx = rem % GW;
        int yy = gy*7 + i, xx = gx*7 + j;
        float v = 0.f;
        if (yy < HIN && xx < WIN_) v = x[((b*3 + c)*HIN + yy)*WIN_ + xx] - c_mean[c];
        sp[p][r] = v;
    }
    __syncthreads();

    for (int t = tid; t < 3200; t += 256) {
        int ocg = t & 7, p = (t >> 3) & 15, pos = t >> 7;
        int pi = pos / 5, pj = pos % 5;
        float acc[8];
        #pragma unroll
        for (int u = 0; u < 8; ++u) acc[u] = b1[ocg*8 + u];
        #pragma unroll
        for (int c = 0; c < 3; ++c)
            #pragma unroll
            for (int ki = 0; ki < 3; ++ki)
                #pragma unroll
                for (int kj = 0; kj < 3; ++kj) {
                    float fv = sp[p][c*49 + (pi+ki)*7 + (pj+kj)];
                    const float* wr = w1t + (c*9 + ki*3 + kj)*64 + ocg*8;
                    const float4 wa = *reinterpret_cast<const float4*>(wr);
                    const float4 wb4 = *reinterpret_cast<const float4*>(wr + 4);
                    acc[0] += fv*wa.x;  acc[1] += fv*wa.y;  acc[2] += fv*wa.z;  acc[3] += fv*wa.w;
                    acc[4] += fv*wb4.x; acc[5] += fv*wb4.y; acc[6] += fv*wb4.z; acc[7] += fv*wb4.w;
                }
        short8 pack;
        #pragma unroll
        for (int u = 0; u < 8; ++u) pack[u] = bf16bits(fmaxf(acc[u], 0.f));
        *reinterpret_cast<short8*>(feat1 + (size_t)pos*(BP*64) + (size_t)(p0 + p)*64 + ocg*8) = pack;
    }
}

// ---------------- conv2: per-tap MFMA, LDS-free -------------------------------------------
__global__ __launch_bounds__(256) void k_conv2(
    const short* __restrict__ feat1, const short* __restrict__ w2b,
    const float* __restrict__ b2, short* __restrict__ feat2)
{
    const int tid = threadIdx.x;
    const int wv = tid >> 6, lane = tid & 63;
    const int n16 = lane & 15, q = lane >> 4;
    const int po = blockIdx.y;
    const int pi = po / 3, pj = po % 3;
    const int p0 = blockIdx.x * 128 + wv * 32;

    f32x4 acc[4][2];
    #pragma unroll
    for (int j = 0; j < 4; ++j) {
        float4 bj = *reinterpret_cast<const float4*>(b2 + j*16 + q*4);
        f32x4 bi = {bj.x, bj.y, bj.z, bj.w};
        acc[j][0] = bi; acc[j][1] = bi;
    }

    for (int ki = 0; ki < 3; ++ki)
        for (int kj = 0; kj < 3; ++kj) {
            const int tap = ki*3 + kj;
            const size_t base = (size_t)((pi+ki)*5 + (pj+kj)) * (BP*64);
            #pragma unroll
            for (int ks = 0; ks < 2; ++ks) {
                short8 af[4];
                #pragma unroll
                for (int j = 0; j < 4; ++j)
                    af[j] = *reinterpret_cast<const short8*>(w2b + (tap*64 + j*16 + n16)*64 + ks*32 + q*8);
                short8 bf[2];
                #pragma unroll
                for (int nt = 0; nt < 2; ++nt) {
                    int pr = p0 + nt*16 + n16; pr = (pr < BP) ? pr : (BP-1);
                    bf[nt] = *reinterpret_cast<const short8*>(feat1 + base + (size_t)pr*64 + ks*32 + q*8);
                }
                #pragma unroll
                for (int j = 0; j < 4; ++j)
                    #pragma unroll
                    for (int nt = 0; nt < 2; ++nt)
                        acc[j][nt] = __builtin_amdgcn_mfma_f32_16x16x32_bf16(af[j], bf[nt], acc[j][nt], 0, 0, 0);
            }
        }

    #pragma unroll
    for (int nt = 0; nt < 2; ++nt) {
        int pr = p0 + nt*16 + n16;
        if (pr >= BP) continue;
        #pragma unroll
        for (int j = 0; j < 4; ++j) {
            short4 pk;
            pk.x = bf16bits(fmaxf(acc[j][nt][0], 0.f));
            pk.y = bf16bits(fmaxf(acc[j][nt][1], 0.f));
            pk.z = bf16bits(fmaxf(acc[j][nt][2], 0.f));
            pk.w = bf16bits(fmaxf(acc[j][nt][3], 0.f));
            *reinterpret_cast<short4*>(feat2 + (size_t)po*(BP*64) + (size_t)pr*64 + j*16 + q*4) = pk;
        }
    }
}

// ---------------- GEMM MFMA: kb2[p][n'=f*32+k] = feat2 @ wkb^T + bias ; N=1024 ------------
__global__ __launch_bounds__(256) void k_gemm(
    const short* __restrict__ feat2, const short* __restrict__ wkb,
    const float* __restrict__ bmg, short* __restrict__ kb2)
{
    __shared__ __align__(16) short As[128*40];
    __shared__ __align__(16) short Bs[128*40];
    const int tid = threadIdx.x;
    const int p0 = blockIdx.x * 128, n0 = blockIdx.y * 128;
    const int wv = tid >> 6, lane = tid & 63;
    const int n16 = lane & 15, q = lane >> 4;
    const int wm = wv & 1, wn = wv >> 1;

    f32x4 acc[4][4] = {};

    for (int k0 = 0; k0 < 576; k0 += 32) {
        const int po = k0 >> 6, cb = k0 & 63;
        for (int t = tid; t < 512; t += 256) {
            int row = t >> 2, seg = t & 3;
            uint4 a = *reinterpret_cast<const uint4*>(wkb + (size_t)(n0 + row)*576 + k0 + seg*8);
            int pr = p0 + row; pr = (pr < BP) ? pr : (BP-1);
            uint4 b = *reinterpret_cast<const uint4*>(feat2 + (size_t)po*(BP*64) + (size_t)pr*64 + cb + seg*8);
            *reinterpret_cast<uint4*>(&As[row*40 + seg*8]) = a;
            *reinterpret_cast<uint4*>(&Bs[row*40 + seg*8]) = b;
        }
        __syncthreads();
        short8 af[4], bf[4];
        #pragma unroll
        for (int mt = 0; mt < 4; ++mt)
            af[mt] = *reinterpret_cast<const short8*>(&As[(wm*64 + mt*16 + n16)*40 + q*8]);
        #pragma unroll
        for (int nt = 0; nt < 4; ++nt)
            bf[nt] = *reinterpret_cast<const short8*>(&Bs[(wn*64 + nt*16 + n16)*40 + q*8]);
        #pragma unroll
        for (int mt = 0; mt < 4; ++mt)
            #pragma unroll
            for (int nt = 0; nt < 4; ++nt)
                acc[mt][nt] = __builtin_amdgcn_mfma_f32_16x16x32_bf16(af[mt], bf[nt], acc[mt][nt], 0, 0, 0);
        __syncthreads();
    }

    #pragma unroll
    for (int nt = 0; nt < 4; ++nt) {
        int pr = p0 + wn*64 + nt*16 + n16;
        if (pr >= BP) continue;
        #pragma unroll
        for (int mt = 0; mt < 4; ++mt) {
            int nb = n0 + wm*64 + mt*16 + q*4;
            float4 bs = *reinterpret_cast<const float4*>(bmg + nb);
            short4 pk;
            pk.x = bf16bits(acc[mt][nt][0] + bs.x);
            pk.y = bf16bits(acc[mt][nt][1] + bs.y);
            pk.z = bf16bits(acc[mt][nt][2] + bs.z);
            pk.w = bf16bits(acc[mt][nt][3] + bs.w);
            *reinterpret_cast<short4*>(kb2 + (size_t)pr*1024 + nb) = pk;
        }
    }
}

// ---------------- apply: per-patch MFMA (C[f][px] = kernT @ win), barrier-free ------------
// wave = one patch; win im2col 64px x 32k in wave-private LDS; 8 MFMAs; packed 8B stores
__global__ __launch_bounds__(256) void k_apply(
    const float* __restrict__ x, const short* __restrict__ kb2, short* __restrict__ y32p)
{
    __shared__ float pp[4][3][9][9];                 // 3.9 KB
    __shared__ __align__(16) short win[4*64*40];     // 20.5 KB, px stride 40 shorts
    const int tid = threadIdx.x;
    const int wv = tid >> 6, lane = tid & 63;
    const int n16 = lane & 15, q = lane >> 4;
    const int p = blockIdx.x * 4 + wv;
    const int b = p / (GH*GW), rem = p % (GH*GW);
    const int gy = rem / GW, gx = rem % GW;
    const size_t kbase = (size_t)p * 1024;

    // zero pp + win rows (wave-private; no barriers anywhere in this kernel)
    float* ppf = &pp[wv][0][0][0];
    for (int t = lane; t < 243; t += 64) ppf[t] = 0.f;
    {
        uint4 z = make_uint4(0u,0u,0u,0u);
        uint4* wr = reinterpret_cast<uint4*>(&win[(wv*64 + lane)*40]);
        #pragma unroll
        for (int u = 0; u < 5; ++u) wr[u] = z;
    }
    // stage patch (own wave)
    for (int t = lane; t < 147; t += 64) {
        int c = t / 49, r = t % 49, i = r / 7, j = r % 7;
        int yy = gy*7 + i, xx = gx*7 + j;
        float v = 0.f;
        if (yy < HIN && xx < WIN_) v = x[((b*3 + c)*HIN + yy)*WIN_ + xx] - c_mean[c];
        pp[wv][c][i+1][j+1] = v;
    }
    // build im2col: lane = px
    if (lane < 49) {
        int h = lane / 7, w = lane % 7;
        short* dst = &win[(wv*64 + lane)*40];
        #pragma unroll
        for (int c = 0; c < 3; ++c)
            #pragma unroll
            for (int i = 0; i < 3; ++i)
                #pragma unroll
                for (int j = 0; j < 3; ++j)
                    dst[c*9 + i*3 + j] = bf16bits(pp[wv][c][h+i][w+j]);
    }

    // A-frags (kernT rows) straight from kb2 global, 16B aligned
    short8 af0 = *reinterpret_cast<const short8*>(kb2 + kbase + (size_t)(n16)*32 + q*8);
    short8 af1 = *reinterpret_cast<const short8*>(kb2 + kbase + (size_t)(16 + n16)*32 + q*8);

    f32x4 acc[2][4];
    #pragma unroll
    for (int mt = 0; mt < 2; ++mt) {
        f32x4 bi;
        #pragma unroll
        for (int r = 0; r < 4; ++r) bi[r] = bits2f(kb2[kbase + (size_t)(mt*16 + q*4 + r)*32 + 27]);
        #pragma unroll
        for (int nt = 0; nt < 4; ++nt) acc[mt][nt] = bi;
    }
    #pragma unroll
    for (int nt = 0; nt < 4; ++nt) {
        short8 bf = *reinterpret_cast<const short8*>(&win[(wv*64 + nt*16 + n16)*40 + q*8]);
        acc[0][nt] = __builtin_amdgcn_mfma_f32_16x16x32_bf16(af0, bf, acc[0][nt], 0, 0, 0);
        acc[1][nt] = __builtin_amdgcn_mfma_f32_16x16x32_bf16(af1, bf, acc[1][nt], 0, 0, 0);
    }

    // D: col=px (n16), row=f (q*4+r) -> 8B packed stores into guarded y32p
    #pragma unroll
    for (int nt = 0; nt < 4; ++nt) {
        int px = nt*16 + n16;
        if (px < 49) {
            int h = px / 7, w = px % 7;
            short* dst = y32p + (((size_t)b*Y32H + gy*7 + h + 2)*Y32W + gx*7 + w + 2)*32;
            #pragma unroll
            for (int mt = 0; mt < 2; ++mt) {
                short4 pk;
                pk.x = bf16bits(acc[mt][nt][0]);
                pk.y = bf16bits(acc[mt][nt][1]);
                pk.z = bf16bits(acc[mt][nt][2]);
                pk.w = bf16bits(acc[mt][nt][3]);
                *reinterpret_cast<short4*>(dst + mt*16 + q*4) = pk;
            }
        }
    }
}

// ---------------- conv3: LDS-staged MFMA, 16x32 px tile, 32->64 5x5 + relu ----------------
__global__ __launch_bounds__(256, 2) void k_conv3(
    const short* __restrict__ y32p, const short* __restrict__ w3b,
    const float* __restrict__ b3, short* __restrict__ y64p)
{
    __shared__ __align__(16) short sin_[20*40*40];   // 62.5 KB, px stride 40 shorts
    const int tid = threadIdx.x;
    const int wv = tid >> 6, lane = tid & 63;
    const int n16 = lane & 15, q = lane >> 4;
    const int x0 = blockIdx.x * 32, y0 = blockIdx.y * 16, b = blockIdx.z;

    for (int t = tid; t < 2880; t += 256) {      // 20 rows x 36 cols x 4 chunks
        int pix = t >> 2, q4 = t & 3;
        int row = pix / 36, col = pix % 36;
        int ry = y0 + row; ry = (ry < Y32H) ? ry : (Y32H - 1);
        int cx = x0 + col; cx = (cx < Y32W) ? cx : (Y32W - 1);
        uint4 v = *reinterpret_cast<const uint4*>(
            y32p + (((size_t)b*Y32H + ry)*Y32W + cx)*32 + q4*8);
        *reinterpret_cast<uint4*>(&sin_[(row*40 + col)*40 + q4*8]) = v;
    }
    __syncthreads();

    f32x4 acc[4][2][4];
    #pragma unroll
    for (int j = 0; j < 4; ++j) {
        float4 bj = *reinterpret_cast<const float4*>(b3 + j*16 + q*4);
        f32x4 bi = {bj.x, bj.y, bj.z, bj.w};
        #pragma unroll
        for (int i = 0; i < 4; ++i) {
            acc[i][0][j] = bi; acc[i][1][j] = bi;
        }
    }

    for (int ky = 0; ky < 5; ++ky) {
        for (int kx = 0; kx < 5; ++kx) {
            const int tap = ky*5 + kx;
            short8 afw[4];
            #pragma unroll
            for (int j = 0; j < 4; ++j)
                afw[j] = *reinterpret_cast<const short8*>(w3b + (tap*64 + j*16 + n16)*32 + q*8);
            short8 bfa[4][2];
            #pragma unroll
            for (int i = 0; i < 4; ++i)
                #pragma unroll
                for (int g = 0; g < 2; ++g) {
                    int pixslot = (wv*4 + i + ky)*40 + (g*16 + n16 + kx);
                    bfa[i][g] = *reinterpret_cast<const short8*>(&sin_[pixslot*40 + q*8]);
                }
            #pragma unroll
            for (int i = 0; i < 4; ++i)
                #pragma unroll
                for (int g = 0; g < 2; ++g)
                    #pragma unroll
                    for (int j = 0; j < 4; ++j)
                        acc[i][g][j] = __builtin_amdgcn_mfma_f32_16x16x32_bf16(afw[j], bfa[i][g], acc[i][g][j], 0, 0, 0);
        }
    }

    #pragma unroll
    for (int g = 0; g < 2; ++g) {
        int ox = x0 + g*16 + n16;
        if (ox >= WP) continue;
        #pragma unroll
        for (int i = 0; i < 4; ++i) {
            int oy = y0 + wv*4 + i;
            if (oy >= HP) continue;
            short* dst = y64p + (((size_t)b*Y64H + oy + 1)*Y64W + ox + 1)*64;
            #pragma unroll
            for (int j = 0; j < 4; ++j) {
                short4 pk;
                pk.x = bf16bits(fmaxf(acc[i][g][j][0], 0.f));
                pk.y = bf16bits(fmaxf(acc[i][g][j][1], 0.f));
                pk.z = bf16bits(fmaxf(acc[i][g][j][2], 0.f));
                pk.w = bf16bits(fmaxf(acc[i][g][j][3], 0.f));
                *reinterpret_cast<short4*>(dst + j*16 + q*4) = pk;
            }
        }
    }
}

// ---------------- conv4: LDS-staged MFMA, 64->12 3x3 + pixel-shuffle + mean ---------------
__global__ __launch_bounds__(256) void k_conv4(
    const short* __restrict__ y64p, const short* __restrict__ w4b,
    const float* __restrict__ b4, float* __restrict__ out)
{
    __shared__ __align__(16) short sin_[18*18*72];   // 46.7 KB, px stride 72 shorts
    const int tid = threadIdx.x;
    const int wv = tid >> 6, lane = tid & 63;
    const int n16 = lane & 15, q = lane >> 4;
    const int x0 = blockIdx.x * 16, y0 = blockIdx.y * 16, b = blockIdx.z;

    for (int t = tid; t < 2592; t += 256) {
        int pix = t >> 3, sub = t & 7;
        int row = pix / 18, col = pix % 18;
        int ry = y0 + row; ry = (ry < Y64H) ? ry : (Y64H - 1);
        int cx = x0 + col;   // <= 641 < 645, always in-bounds
        uint4 v = *reinterpret_cast<const uint4*>(
            y64p + (((size_t)b*Y64H + ry)*Y64W + cx)*64 + sub*8);
        *reinterpret_cast<uint4*>(&sin_[pix*72 + sub*8]) = v;
    }
    __syncthreads();

    f32x4 acc[4];
    {
        f32x4 bi = {0.f, 0.f, 0.f, 0.f};
        if (q < 3) {
            float4 bq = *reinterpret_cast<const float4*>(b4 + q*4);
            bi = {bq.x, bq.y, bq.z, bq.w};
        }
        #pragma unroll
        for (int i = 0; i < 4; ++i) acc[i] = bi;
    }

    for (int ky = 0; ky < 3; ++ky) {
        #pragma unroll
        for (int kx = 0; kx < 3; ++kx) {
            const int tap = ky*3 + kx;
            short8 af0 = *reinterpret_cast<const short8*>(w4b + ((tap*2 + 0)*16 + n16)*32 + q*8);
            short8 af1 = *reinterpret_cast<const short8*>(w4b + ((tap*2 + 1)*16 + n16)*32 + q*8);
            #pragma unroll
            for (int i = 0; i < 4; ++i) {
                int pix = (wv*4 + i + ky)*18 + (n16 + kx);
                short8 a0 = *reinterpret_cast<const short8*>(&sin_[pix*72 + q*8]);
                short8 a1 = *reinterpret_cast<const short8*>(&sin_[pix*72 + 32 + q*8]);
                acc[i] = __builtin_amdgcn_mfma_f32_16x16x32_bf16(af0, a0, acc[i], 0, 0, 0);
                acc[i] = __builtin_amdgcn_mfma_f32_16x16x32_bf16(af1, a1, acc[i], 0, 0, 0);
            }
        }
    }

    if (q < 3) {
        const int xx = x0 + n16;
        const float m = c_mean[q];
        #pragma unroll
        for (int i = 0; i < 4; ++i) {
            int yy = y0 + wv*4 + i;
            if (yy >= HIN) continue;
            size_t r0 = ((size_t)(b*3 + q)*720 + yy*2)*1280 + xx*2;
            float2 s0 = {acc[i][0] + m, acc[i][1] + m};
            float2 s1 = {acc[i][2] + m, acc[i][3] + m};
            *reinterpret_cast<float2*>(out + r0) = s0;
            *reinterpret_cast<float2*>(out + r0 + 1280) = s1;
        }
    }
}

extern "C" void kernel_launch(void* const* d_in, const int* in_sizes, int n_in,
                              void* d_out, int out_size, void* d_ws, size_t ws_size,
                              hipStream_t stream) {
    const float* x  = (const float*)d_in[0];
    const float* w1 = (const float*)d_in[1];
    const float* b1 = (const float*)d_in[2];
    const float* w2 = (const float*)d_in[3];
    const float* b2 = (const float*)d_in[4];
    const float* wk = (const float*)d_in[5];
    const float* bk = (const float*)d_in[6];
    const float* wb = (const float*)d_in[7];
    const float* bb = (const float*)d_in[8];
    const float* w3 = (const float*)d_in[9];
    const float* b3 = (const float*)d_in[10];
    const float* w4 = (const float*)d_in[11];
    const float* b4 = (const float*)d_in[12];
    float* out = (float*)d_out;

    if (ws_size < WS_NEED) return;

    char* ws = (char*)d_ws;
    short* feat1 = (short*)(ws + OFF_FEAT1);
    short* feat2 = (short*)(ws + OFF_FEAT2);
    short* kb2   = (short*)(ws + OFF_KB2);
    short* y32p  = (short*)(ws + OFF_Y32P);
    short* y64p  = (short*)(ws + OFF_Y64P);
    float* bmg = (float*)(ws + OFF_BMG);
    float* w1t = (float*)(ws + OFF_W1T);
    short* w2b = (short*)(ws + OFF_W2B);
    short* wkb = (short*)(ws + OFF_WKB);
    short* w3b = (short*)(ws + OFF_W3B);
    short* w4b = (short*)(ws + OFF_W4B);

    k_prep <<<2304, 256, 0, stream>>>(w1, w1t, w2, w2b, wk, wb, wkb, bk, bb, bmg, w3, w3b, w4, w4b);
    k_zg32 <<<254, 256, 0, stream>>>(y32p);
    k_conv1<<<BP/16, 256, 0, stream>>>(x, w1t, b1, feat1);
    k_conv2<<<dim3(150, 9), 256, 0, stream>>>(feat1, w2b, b2, feat2);
    k_gemm <<<dim3(150, 8), 256, 0, stream>>>(feat2, wkb, bmg, kb2);
    k_apply<<<BP/4, 256, 0, stream>>>(x, kb2, y32p);
    k_zg64 <<<127, 256, 0, stream>>>(y64p);   // ONLY here: feat1/feat2/kb2 (aliased by y64p) all dead
    k_conv3<<<dim3(21, 23, 4), 256, 0, stream>>>(y32p, w3b, b3, y64p);
    k_conv4<<<dim3(40, 23, 4), 256, 0, stream>>>(y64p, w4b, b4, out);
}